// Round 1
// baseline (311.523 us; speedup 1.0000x reference)
//
#include <hip/hip_runtime.h>
#include <cstdint>

// ---- problem constants ----
// B=8, T=1024, E=128, H=1024, NH=16, HD=64, S=T+E=1152
// inputs fp32; compute in bf16 MFMA with fp32 accum.

typedef __attribute__((ext_vector_type(8))) short s16x8;   // 8 bf16 (4 VGPR) MFMA operand
typedef __attribute__((ext_vector_type(4))) float f32x4;   // MFMA accumulator
typedef __attribute__((ext_vector_type(4))) unsigned short u16x4;

#define DEVFN static __device__ __forceinline__

DEVFN unsigned short f2bf(float f) {  // RNE float->bf16
  uint32_t u = __builtin_bit_cast(uint32_t, f);
  u += 0x7fffu + ((u >> 16) & 1u);
  return (unsigned short)(u >> 16);
}

DEVFN void gload16(const void* g, void* lds) {  // async global->LDS, 16B/lane
  using GP = const __attribute__((address_space(1))) uint32_t*;
  using LP = __attribute__((address_space(3))) uint32_t*;
  __builtin_amdgcn_global_load_lds(
      reinterpret_cast<GP>(reinterpret_cast<uintptr_t>(g)),
      reinterpret_cast<LP>((uint32_t)reinterpret_cast<uintptr_t>(lds)),
      16, 0, 0);
}

// ---------------- prep: fp32 -> bf16 casts (+ pos_ent fuse) ----------------
// ws bf16 layout (elements):
//   tokBF  @ 0        : 8388608   (tok [8192][1024])
//   peBF   @ 8388608  : 1048576   ((ent+qpos)*0.5 [1024][1024])
//   entBF  @ 9437184  : 1048576
//   WBF    @ 10485760 : 6*1048576 (Wq,Wk,Wv,Weq,Wek,Wev; row-major [n][k] = B^T layout)
//   Qb     @ 16777216 : 9437184   ([bh][s][64])
//   Kb     @ 26214400 : 9437184   ([bh][s][64])
//   Vtb    @ 35651584 : 9437184   ([bh][64][s]  <- transposed for PV B-operand)
__global__ __launch_bounds__(256) void prep_kernel(
    const float* __restrict__ tok, const float* __restrict__ ent,
    const float* __restrict__ qpos,
    const float* __restrict__ W0, const float* __restrict__ W1,
    const float* __restrict__ W2, const float* __restrict__ W3,
    const float* __restrict__ W4, const float* __restrict__ W5,
    unsigned short* __restrict__ dst)
{
  const int NG = 4194304;  // 16777216 elems / 4
  for (int g = blockIdx.x * blockDim.x + threadIdx.x; g < NG;
       g += gridDim.x * blockDim.x) {
    int e = g << 2;
    f32x4 v;
    if (e < 8388608) {
      v = *(const f32x4*)(tok + e);
    } else if (e < 9437184) {
      int i = e - 8388608;
      f32x4 a = *(const f32x4*)(ent + i);
      f32x4 p = *(const f32x4*)(qpos + i);
      v = (a + p) * 0.5f;
    } else if (e < 10485760) {
      v = *(const f32x4*)(ent + (e - 9437184));
    } else {
      int i = e - 10485760;
      int wsel = i >> 20;
      const float* W = wsel == 0 ? W0 : wsel == 1 ? W1 : wsel == 2 ? W2
                     : wsel == 3 ? W3 : wsel == 4 ? W4 : W5;
      v = *(const f32x4*)(W + (i & 1048575));
    }
    u16x4 o;
#pragma unroll
    for (int j = 0; j < 4; ++j) o[j] = f2bf(v[j]);
    *(u16x4*)(dst + e) = o;
  }
}

// ---------------- projection GEMM (m97 structure) ----------------
// C[i][j] = sum_k A[i][k] * W[j][k]  (+bias[j]), 128x128 tile, BK=32.
// grid = (24, 72): bx -> {Q,K,V} x 8 col tiles; by<64 -> token rows, else entity.
// Staged via global_load_lds with XOR-swizzled SOURCE (linear LDS dest) and
// the same swizzle on LDS reads: swzByte(row) = ((row>>1)&3)<<4 within 64B row.
__global__ __launch_bounds__(256) void proj_gemm(
    const unsigned short* __restrict__ Atok, const unsigned short* __restrict__ Ape,
    const unsigned short* __restrict__ Aent, const unsigned short* __restrict__ Wb6,
    const float* __restrict__ b0, const float* __restrict__ b1,
    const float* __restrict__ b2, const float* __restrict__ b3,
    const float* __restrict__ b4, const float* __restrict__ b5,
    unsigned short* __restrict__ Qo, unsigned short* __restrict__ Ko,
    unsigned short* __restrict__ Vt)
{
  __shared__ __align__(16) unsigned short As[128 * 32];
  __shared__ __align__(16) unsigned short Bs[128 * 32];

  const int tid = threadIdx.x;
  const int l = tid & 63, w = tid >> 6;
  const int lr = l & 15, lg = l >> 4;
  const int bx = blockIdx.x, by = blockIdx.y;
  const int which = bx >> 3;            // 0=Q 1=K 2=V
  const int n0l = (bx & 7) << 7;        // col tile within [0,1024)
  const bool entm = by >= 64;
  const int byl = entm ? by - 64 : by;
  const int wsel = which + (entm ? 3 : 0);
  const unsigned short* A = entm ? (which == 2 ? Aent : Ape) : Atok;
  const unsigned short* Wp = Wb6 + (size_t)wsel * 1048576;
  const float* bias = entm ? (which == 0 ? b3 : which == 1 ? b4 : b5)
                           : (which == 0 ? b0 : which == 1 ? b1 : b2);
  const int bShift = entm ? 7 : 10;
  const int sBase = entm ? 1024 : 0;

  // staging geometry: 8 chunks of 1KB per tile; wave w owns chunks 2w,2w+1
  const int c0 = w * 2, c1 = w * 2 + 1;
  const int sr0 = c0 * 16 + (l >> 2), sr1 = c1 * 16 + (l >> 2);
  const int sc0 = ((l & 3) * 8) ^ (((sr0 >> 1) & 3) << 3);  // pre-swizzled source col
  const int sc1 = ((l & 3) * 8) ^ (((sr1 >> 1) & 3) << 3);
  const unsigned short* gA0 = A + (size_t)(byl * 128 + sr0) * 1024 + sc0;
  const unsigned short* gA1 = A + (size_t)(byl * 128 + sr1) * 1024 + sc1;
  const unsigned short* gB0 = Wp + (size_t)(n0l + sr0) * 1024 + sc0;
  const unsigned short* gB1 = Wp + (size_t)(n0l + sr1) * 1024 + sc1;
  unsigned short* lA0 = As + c0 * 512; unsigned short* lA1 = As + c1 * 512;
  unsigned short* lB0 = Bs + c0 * 512; unsigned short* lB1 = Bs + c1 * 512;

  const int wr = w >> 1, wc = w & 1;  // wave's 64x64 quadrant
  int offA[4], offB[4];
#pragma unroll
  for (int mi = 0; mi < 4; ++mi) {
    int row = wr * 64 + mi * 16 + lr;
    offA[mi] = row * 32 + ((lg * 8) ^ (((row >> 1) & 3) << 3));
  }
#pragma unroll
  for (int ni = 0; ni < 4; ++ni) {
    int row = wc * 64 + ni * 16 + lr;
    offB[ni] = row * 32 + ((lg * 8) ^ (((row >> 1) & 3) << 3));
  }

  f32x4 acc[4][4] = {};
  for (int kt = 0; kt < 32; ++kt) {
    const int ko = kt * 32;
    gload16(gA0 + ko, lA0);
    gload16(gA1 + ko, lA1);
    gload16(gB0 + ko, lB0);
    gload16(gB1 + ko, lB1);
    __syncthreads();
    s16x8 a[4], b[4];
#pragma unroll
    for (int mi = 0; mi < 4; ++mi) a[mi] = *(const s16x8*)(As + offA[mi]);
#pragma unroll
    for (int ni = 0; ni < 4; ++ni) b[ni] = *(const s16x8*)(Bs + offB[ni]);
#pragma unroll
    for (int mi = 0; mi < 4; ++mi)
#pragma unroll
      for (int ni = 0; ni < 4; ++ni)
        acc[mi][ni] = __builtin_amdgcn_mfma_f32_16x16x32_bf16(
            a[mi], b[ni], acc[mi][ni], 0, 0, 0);
    __syncthreads();
  }

  // epilogue: +bias, bf16, scatter into attention layouts
  const int bMask = (1 << bShift) - 1;
#pragma unroll
  for (int mi = 0; mi < 4; ++mi) {
    const int i0 = byl * 128 + wr * 64 + mi * 16 + lg * 4;
#pragma unroll
    for (int ni = 0; ni < 4; ++ni) {
      const int j = n0l + wc * 64 + ni * 16 + lr;  // 0..1023
      const float bv = bias[j];
      const int h = j >> 6, d = j & 63;
      if (which < 2) {
        unsigned short* dst = (which == 0) ? Qo : Ko;
#pragma unroll
        for (int r = 0; r < 4; ++r) {
          const int i = i0 + r;
          const int bidx = i >> bShift;
          const int s = sBase + (i & bMask);
          dst[((size_t)(bidx * 16 + h) * 1152 + s) * 64 + d] =
              f2bf(acc[mi][ni][r] + bv);
        }
      } else {  // V transposed: [bh][d][s]; 4 consecutive s pack into one 8B store
        const int bidx = i0 >> bShift;
        const int s0 = sBase + (i0 & bMask);
        u16x4 pk;
#pragma unroll
        for (int r = 0; r < 4; ++r) pk[r] = f2bf(acc[mi][ni][r] + bv);
        *(u16x4*)(Vt + ((size_t)(bidx * 16 + h) * 64 + d) * 1152 + s0) = pk;
      }
    }
  }
}

// ---------------- flash attention ----------------
// grid = (9 q-tiles, 128 bh). 4 waves x 32 q-rows, KV tile 64, online softmax.
DEVFN float rmax16(float v) {
#pragma unroll
  for (int d = 1; d < 16; d <<= 1) v = fmaxf(v, __shfl_xor(v, d));
  return v;
}
DEVFN float rsum16(float v) {
#pragma unroll
  for (int d = 1; d < 16; d <<= 1) v += __shfl_xor(v, d);
  return v;
}

__global__ __launch_bounds__(256) void attn_kernel(
    const unsigned short* __restrict__ Q, const unsigned short* __restrict__ K,
    const unsigned short* __restrict__ Vt, const float* __restrict__ mask,
    float* __restrict__ out)
{
  __shared__ __align__(16) unsigned short Plds[4][32 * 64];  // per-wave P, swizzled
  const int tid = threadIdx.x, l = tid & 63, w = tid >> 6;
  const int lr = l & 15, lg = l >> 4;
  const int qt = blockIdx.x, bh = blockIdx.y;
  const int b = bh >> 4, h = bh & 15;
  const unsigned short* Qh = Q + (size_t)bh * 73728;
  const unsigned short* Kh = K + (size_t)bh * 73728;
  const unsigned short* Vh = Vt + (size_t)bh * 73728;  // [64][1152]
  const float* mrow = mask + b * 1152;
  const int q0 = qt * 128 + w * 32;
  char* PwB = (char*)&Plds[w][0];
  const f32x4 fz = {0.f, 0.f, 0.f, 0.f};

  s16x8 qa[2][2];
#pragma unroll
  for (int mi = 0; mi < 2; ++mi)
#pragma unroll
    for (int ks = 0; ks < 2; ++ks)
      qa[mi][ks] =
          *(const s16x8*)(Qh + (size_t)(q0 + mi * 16 + lr) * 64 + ks * 32 + lg * 8);

  f32x4 O[2][4] = {};
  float mrun[2][4], lrun[2][4];
#pragma unroll
  for (int mi = 0; mi < 2; ++mi)
#pragma unroll
    for (int r = 0; r < 4; ++r) { mrun[mi][r] = -1e30f; lrun[mi][r] = 0.f; }

  for (int kv0 = 0; kv0 < 1152; kv0 += 64) {
    // ---- scores = Q K^T * 0.125 + mask ----
    f32x4 sc[2][4];
#pragma unroll
    for (int ni = 0; ni < 4; ++ni) {
      const unsigned short* kp = Kh + (size_t)(kv0 + ni * 16 + lr) * 64 + lg * 8;
      s16x8 kb0 = *(const s16x8*)(kp);
      s16x8 kb1 = *(const s16x8*)(kp + 32);
#pragma unroll
      for (int mi = 0; mi < 2; ++mi) {
        f32x4 t = __builtin_amdgcn_mfma_f32_16x16x32_bf16(qa[mi][0], kb0, fz, 0, 0, 0);
        t = __builtin_amdgcn_mfma_f32_16x16x32_bf16(qa[mi][1], kb1, t, 0, 0, 0);
        sc[mi][ni] = t;
      }
    }
    float mv[4];
#pragma unroll
    for (int ni = 0; ni < 4; ++ni) mv[ni] = mrow[kv0 + ni * 16 + lr];
#pragma unroll
    for (int mi = 0; mi < 2; ++mi)
#pragma unroll
      for (int ni = 0; ni < 4; ++ni) sc[mi][ni] = sc[mi][ni] * 0.125f + mv[ni];

    // ---- online softmax ----
    float al[2][4];
#pragma unroll
    for (int mi = 0; mi < 2; ++mi)
#pragma unroll
      for (int r = 0; r < 4; ++r) {
        float tm = fmaxf(fmaxf(sc[mi][0][r], sc[mi][1][r]),
                         fmaxf(sc[mi][2][r], sc[mi][3][r]));
        tm = rmax16(tm);
        float mn = fmaxf(mrun[mi][r], tm);
        al[mi][r] = __expf(mrun[mi][r] - mn);
        mrun[mi][r] = mn;
      }
#pragma unroll
    for (int mi = 0; mi < 2; ++mi)
#pragma unroll
      for (int r = 0; r < 4; ++r) {
        float rs = 0.f;
#pragma unroll
        for (int ni = 0; ni < 4; ++ni) {
          float p = __expf(sc[mi][ni][r] - mrun[mi][r]);
          sc[mi][ni][r] = p;
          rs += p;
        }
        rs = rsum16(rs);
        lrun[mi][r] = lrun[mi][r] * al[mi][r] + rs;
#pragma unroll
        for (int di = 0; di < 4; ++di) O[mi][di][r] *= al[mi][r];
      }

    // ---- P -> wave-private LDS (bf16, XOR swizzle byte^=((row&7)<<4)) ----
#pragma unroll
    for (int mi = 0; mi < 2; ++mi)
#pragma unroll
      for (int ni = 0; ni < 4; ++ni)
#pragma unroll
        for (int r = 0; r < 4; ++r) {
          int row = mi * 16 + lg * 4 + r;
          int colB = ((ni * 16 + lr) * 2) ^ ((row & 7) << 4);
          *(unsigned short*)(PwB + row * 128 + colB) = f2bf(sc[mi][ni][r]);
        }

    // ---- O += P V ----
#pragma unroll
    for (int ks = 0; ks < 2; ++ks) {
      s16x8 pa[2];
#pragma unroll
      for (int mi = 0; mi < 2; ++mi) {
        int row = mi * 16 + lr;
        int colB = (ks * 64 + lg * 16) ^ ((row & 7) << 4);
        pa[mi] = *(const s16x8*)(PwB + row * 128 + colB);
      }
#pragma unroll
      for (int di = 0; di < 4; ++di) {
        s16x8 vb = *(const s16x8*)(Vh + (size_t)(di * 16 + lr) * 1152 + kv0 +
                                   ks * 32 + lg * 8);
#pragma unroll
        for (int mi = 0; mi < 2; ++mi)
          O[mi][di] =
              __builtin_amdgcn_mfma_f32_16x16x32_bf16(pa[mi], vb, O[mi][di], 0, 0, 0);
      }
    }
  }

  // ---- normalize + write fp32 output (split tok/ent regions) ----
#pragma unroll
  for (int mi = 0; mi < 2; ++mi)
#pragma unroll
    for (int r = 0; r < 4; ++r) {
      const float inv = 1.0f / lrun[mi][r];
      const int s = q0 + mi * 16 + lg * 4 + r;
      const size_t base =
          (s < 1024) ? ((size_t)(b * 1024 + s) * 1024 + h * 64)
                     : (8388608u + (size_t)(b * 128 + (s - 1024)) * 1024 + h * 64);
#pragma unroll
      for (int di = 0; di < 4; ++di)
        out[base + di * 16 + lr] = O[mi][di][r] * inv;
    }
}

// ---------------- launch ----------------
extern "C" void kernel_launch(void* const* d_in, const int* in_sizes, int n_in,
                              void* d_out, int out_size, void* d_ws, size_t ws_size,
                              hipStream_t stream) {
  const float* tok  = (const float*)d_in[0];
  const float* ent  = (const float*)d_in[1];
  const float* mask = (const float*)d_in[2];
  const float* qpos = (const float*)d_in[3];
  const float* Wq  = (const float*)d_in[4];  const float* bq  = (const float*)d_in[5];
  const float* Wk  = (const float*)d_in[6];  const float* bk  = (const float*)d_in[7];
  const float* Wv  = (const float*)d_in[8];  const float* bv  = (const float*)d_in[9];
  const float* Weq = (const float*)d_in[10]; const float* beq = (const float*)d_in[11];
  const float* Wek = (const float*)d_in[12]; const float* bek = (const float*)d_in[13];
  const float* Wev = (const float*)d_in[14]; const float* bev = (const float*)d_in[15];
  float* out = (float*)d_out;

  unsigned short* ws = (unsigned short*)d_ws;
  unsigned short* tokBF = ws;
  unsigned short* peBF  = ws + 8388608;
  unsigned short* entBF = ws + 9437184;
  unsigned short* WBF   = ws + 10485760;
  unsigned short* Qb    = ws + 16777216;
  unsigned short* Kb    = ws + 26214400;
  unsigned short* Vtb   = ws + 35651584;

  prep_kernel<<<2048, 256, 0, stream>>>(tok, ent, qpos, Wq, Wk, Wv, Weq, Wek, Wev, ws);
  proj_gemm<<<dim3(24, 72), 256, 0, stream>>>(tokBF, peBF, entBF, WBF,
                                              bq, bk, bv, beq, bek, bev,
                                              Qb, Kb, Vtb);
  attn_kernel<<<dim3(9, 128), 256, 0, stream>>>(Qb, Kb, Vtb, mask, out);
}

// Round 2
// 285.875 us; speedup vs baseline: 1.0897x; 1.0897x over previous
//
#include <hip/hip_runtime.h>
#include <cstdint>

// ---- problem constants ----
// B=8, T=1024, E=128, H=1024, NH=16, HD=64, S=T+E=1152
// inputs fp32; compute in bf16 MFMA with fp32 accum.

typedef __attribute__((ext_vector_type(8))) short s16x8;   // 8 bf16 (4 VGPR) MFMA operand
typedef __attribute__((ext_vector_type(4))) float f32x4;   // MFMA accumulator
typedef __attribute__((ext_vector_type(4))) unsigned short u16x4;
typedef __attribute__((ext_vector_type(4))) unsigned int u32x4;

#define DEVFN static __device__ __forceinline__

DEVFN unsigned short f2bf(float f) {  // RNE float->bf16
  uint32_t u = __builtin_bit_cast(uint32_t, f);
  u += 0x7fffu + ((u >> 16) & 1u);
  return (unsigned short)(u >> 16);
}

DEVFN void gload16(const void* g, void* lds) {  // async global->LDS, 16B/lane
  using GP = const __attribute__((address_space(1))) uint32_t*;
  using LP = __attribute__((address_space(3))) uint32_t*;
  __builtin_amdgcn_global_load_lds(
      reinterpret_cast<GP>(reinterpret_cast<uintptr_t>(g)),
      reinterpret_cast<LP>((uint32_t)reinterpret_cast<uintptr_t>(lds)),
      16, 0, 0);
}

// cross-lane pair values via permlane swaps (VALU-only, no DS latency).
// After sw16f: x holds the even-group-of-16 copy, y the odd-group copy,
// both at the caller's within-group lane index -> op(x,y) = pairwise reduce.
DEVFN void sw16f(float v, float& x, float& y) {
  uint32_t a = __builtin_bit_cast(uint32_t, v), b = a;
  asm("v_permlane16_swap_b32 %0, %1" : "+v"(a), "+v"(b));
  x = __builtin_bit_cast(float, a);
  y = __builtin_bit_cast(float, b);
}
DEVFN void sw32f(float v, float& x, float& y) {
  uint32_t a = __builtin_bit_cast(uint32_t, v), b = a;
  asm("v_permlane32_swap_b32 %0, %1" : "+v"(a), "+v"(b));
  x = __builtin_bit_cast(float, a);
  y = __builtin_bit_cast(float, b);
}
DEVFN float redmax64(float v) {  // reduce-max across the 4 lane-groups
  float a, b;
  sw16f(v, a, b); v = fmaxf(a, b);
  sw32f(v, a, b); return fmaxf(a, b);
}
DEVFN float redsum64(float v) {
  float a, b;
  sw16f(v, a, b); v = a + b;
  sw32f(v, a, b); return a + b;
}
DEVFN uint32_t pk_bf16(float lo, float hi) {  // {lo16: bf16(lo), hi16: bf16(hi)}
  uint32_t r;
  asm("v_cvt_pk_bf16_f32 %0, %1, %2" : "=v"(r) : "v"(lo), "v"(hi));
  return r;
}
DEVFN f32x4 vmax4(f32x4 a, f32x4 b) {
  f32x4 r;
#pragma unroll
  for (int i = 0; i < 4; ++i) r[i] = fmaxf(a[i], b[i]);
  return r;
}

// ---------------- prep: fp32 -> bf16 casts (+ pos_ent fuse) ----------------
// ws bf16 layout (elements):
//   tokBF  @ 0        : 8388608   (tok [8192][1024])
//   peBF   @ 8388608  : 1048576   ((ent+qpos)*0.5 [1024][1024])
//   entBF  @ 9437184  : 1048576
//   WBF    @ 10485760 : 6*1048576 (Wq,Wk,Wv,Weq,Wek,Wev; row-major [n][k] = B^T layout)
//   Qb     @ 16777216 : 9437184   ([bh][s][64], pre-scaled by 0.125)
//   Kb     @ 26214400 : 9437184   ([bh][s][64])
//   Vtb    @ 35651584 : 9437184   ([bh][64][s]  <- transposed for PV)
__global__ __launch_bounds__(256) void prep_kernel(
    const float* __restrict__ tok, const float* __restrict__ ent,
    const float* __restrict__ qpos,
    const float* __restrict__ W0, const float* __restrict__ W1,
    const float* __restrict__ W2, const float* __restrict__ W3,
    const float* __restrict__ W4, const float* __restrict__ W5,
    unsigned short* __restrict__ dst)
{
  const int NG = 4194304;  // 16777216 elems / 4
  for (int g = blockIdx.x * blockDim.x + threadIdx.x; g < NG;
       g += gridDim.x * blockDim.x) {
    int e = g << 2;
    f32x4 v;
    if (e < 8388608) {
      v = *(const f32x4*)(tok + e);
    } else if (e < 9437184) {
      int i = e - 8388608;
      f32x4 a = *(const f32x4*)(ent + i);
      f32x4 p = *(const f32x4*)(qpos + i);
      v = (a + p) * 0.5f;
    } else if (e < 10485760) {
      v = *(const f32x4*)(ent + (e - 9437184));
    } else {
      int i = e - 10485760;
      int wsel = i >> 20;
      const float* W = wsel == 0 ? W0 : wsel == 1 ? W1 : wsel == 2 ? W2
                     : wsel == 3 ? W3 : wsel == 4 ? W4 : W5;
      v = *(const f32x4*)(W + (i & 1048575));
    }
    u16x4 o;
#pragma unroll
    for (int j = 0; j < 4; ++j) o[j] = f2bf(v[j]);
    *(u16x4*)(dst + e) = o;
  }
}

// ---------------- projection GEMM (m97 structure) ----------------
__global__ __launch_bounds__(256) void proj_gemm(
    const unsigned short* __restrict__ Atok, const unsigned short* __restrict__ Ape,
    const unsigned short* __restrict__ Aent, const unsigned short* __restrict__ Wb6,
    const float* __restrict__ b0, const float* __restrict__ b1,
    const float* __restrict__ b2, const float* __restrict__ b3,
    const float* __restrict__ b4, const float* __restrict__ b5,
    unsigned short* __restrict__ Qo, unsigned short* __restrict__ Ko,
    unsigned short* __restrict__ Vt)
{
  __shared__ __align__(16) unsigned short As[128 * 32];
  __shared__ __align__(16) unsigned short Bs[128 * 32];

  const int tid = threadIdx.x;
  const int l = tid & 63, w = tid >> 6;
  const int lr = l & 15, lg = l >> 4;
  const int bx = blockIdx.x, by = blockIdx.y;
  const int which = bx >> 3;            // 0=Q 1=K 2=V
  const int n0l = (bx & 7) << 7;        // col tile within [0,1024)
  const bool entm = by >= 64;
  const int byl = entm ? by - 64 : by;
  const int wsel = which + (entm ? 3 : 0);
  const unsigned short* A = entm ? (which == 2 ? Aent : Ape) : Atok;
  const unsigned short* Wp = Wb6 + (size_t)wsel * 1048576;
  const float* bias = entm ? (which == 0 ? b3 : which == 1 ? b4 : b5)
                           : (which == 0 ? b0 : which == 1 ? b1 : b2);
  const int bShift = entm ? 7 : 10;
  const int sBase = entm ? 1024 : 0;
  const float qscale = (which == 0) ? 0.125f : 1.0f;  // fold 1/sqrt(HD) into Q

  const int c0 = w * 2, c1 = w * 2 + 1;
  const int sr0 = c0 * 16 + (l >> 2), sr1 = c1 * 16 + (l >> 2);
  const int sc0 = ((l & 3) * 8) ^ (((sr0 >> 1) & 3) << 3);
  const int sc1 = ((l & 3) * 8) ^ (((sr1 >> 1) & 3) << 3);
  const unsigned short* gA0 = A + (size_t)(byl * 128 + sr0) * 1024 + sc0;
  const unsigned short* gA1 = A + (size_t)(byl * 128 + sr1) * 1024 + sc1;
  const unsigned short* gB0 = Wp + (size_t)(n0l + sr0) * 1024 + sc0;
  const unsigned short* gB1 = Wp + (size_t)(n0l + sr1) * 1024 + sc1;
  unsigned short* lA0 = As + c0 * 512; unsigned short* lA1 = As + c1 * 512;
  unsigned short* lB0 = Bs + c0 * 512; unsigned short* lB1 = Bs + c1 * 512;

  const int wr = w >> 1, wc = w & 1;
  int offA[4], offB[4];
#pragma unroll
  for (int mi = 0; mi < 4; ++mi) {
    int row = wr * 64 + mi * 16 + lr;
    offA[mi] = row * 32 + ((lg * 8) ^ (((row >> 1) & 3) << 3));
  }
#pragma unroll
  for (int ni = 0; ni < 4; ++ni) {
    int row = wc * 64 + ni * 16 + lr;
    offB[ni] = row * 32 + ((lg * 8) ^ (((row >> 1) & 3) << 3));
  }

  f32x4 acc[4][4] = {};
  for (int kt = 0; kt < 32; ++kt) {
    const int ko = kt * 32;
    gload16(gA0 + ko, lA0);
    gload16(gA1 + ko, lA1);
    gload16(gB0 + ko, lB0);
    gload16(gB1 + ko, lB1);
    __syncthreads();
    s16x8 a[4], b[4];
#pragma unroll
    for (int mi = 0; mi < 4; ++mi) a[mi] = *(const s16x8*)(As + offA[mi]);
#pragma unroll
    for (int ni = 0; ni < 4; ++ni) b[ni] = *(const s16x8*)(Bs + offB[ni]);
#pragma unroll
    for (int mi = 0; mi < 4; ++mi)
#pragma unroll
      for (int ni = 0; ni < 4; ++ni)
        acc[mi][ni] = __builtin_amdgcn_mfma_f32_16x16x32_bf16(
            a[mi], b[ni], acc[mi][ni], 0, 0, 0);
    __syncthreads();
  }

  const int bMask = (1 << bShift) - 1;
#pragma unroll
  for (int mi = 0; mi < 4; ++mi) {
    const int i0 = byl * 128 + wr * 64 + mi * 16 + lg * 4;
#pragma unroll
    for (int ni = 0; ni < 4; ++ni) {
      const int j = n0l + wc * 64 + ni * 16 + lr;
      const float bv = bias[j];
      const int h = j >> 6, d = j & 63;
      if (which < 2) {
        unsigned short* dst = (which == 0) ? Qo : Ko;
#pragma unroll
        for (int r = 0; r < 4; ++r) {
          const int i = i0 + r;
          const int bidx = i >> bShift;
          const int s = sBase + (i & bMask);
          dst[((size_t)(bidx * 16 + h) * 1152 + s) * 64 + d] =
              f2bf((acc[mi][ni][r] + bv) * qscale);
        }
      } else {
        const int bidx = i0 >> bShift;
        const int s0 = sBase + (i0 & bMask);
        u16x4 pk;
#pragma unroll
        for (int r = 0; r < 4; ++r) pk[r] = f2bf(acc[mi][ni][r] + bv);
        *(u16x4*)(Vt + ((size_t)(bidx * 16 + h) * 64 + d) * 1152 + s0) = pk;
      }
    }
  }
}

// ---------------- flash attention (swapped operands, register softmax) -----
// grid = (9 q-tiles, 128 bh). 4 waves x 32 q-rows, KV tile 64.
// S^T = mfma(K, Q): lane holds S^T[kv = ni*16+g*4+r][q = mi*16+c], c=l&15, g=l>>4.
// Softmax fully in-register (in-lane tree + permlane cross-group combine).
// P^T fragments built with cvt_pk + permlane{32,16}_swap; O^T = mfma(V^T, P^T)
// so the rescale is a per-lane scalar. One LDS transpose at the end.
__global__ __launch_bounds__(256) void attn_kernel(
    const unsigned short* __restrict__ Q, const unsigned short* __restrict__ K,
    const unsigned short* __restrict__ Vt, const float* __restrict__ mask,
    float* __restrict__ out)
{
  __shared__ float Tr[4][64][33];  // per-wave O^T -> O transpose buffer
  const int tid = threadIdx.x, l = tid & 63, w = tid >> 6;
  const int c = l & 15, g = l >> 4;
  const int qt = blockIdx.x, bh = blockIdx.y;
  const int b = bh >> 4, h = bh & 15;
  const unsigned short* Qh = Q + (size_t)bh * 73728;
  const unsigned short* Kh = K + (size_t)bh * 73728;
  const unsigned short* Vh = Vt + (size_t)bh * 73728;  // [64][1152]
  const float* mrow = mask + b * 1152;
  const int q0 = qt * 128 + w * 32;
  const f32x4 fz = {0.f, 0.f, 0.f, 0.f};

  // Q as B-operand: lane holds Q[q0+mi*16+c][ds*32 + g*8 + j]
  s16x8 qb[2][2];
#pragma unroll
  for (int mi = 0; mi < 2; ++mi)
#pragma unroll
    for (int ds = 0; ds < 2; ++ds)
      qb[mi][ds] =
          *(const s16x8*)(Qh + (size_t)(q0 + mi * 16 + c) * 64 + ds * 32 + g * 8);

  f32x4 OT[2][4] = {};              // O^T[d=di*16+g*4+r][q=mi*16+c]
  float mrun[2] = {-1e30f, -1e30f}, lrun[2] = {0.f, 0.f};

  for (int kv0 = 0; kv0 < 1152; kv0 += 64) {
    // ---- S^T = K Q^T (Q pre-scaled), + mask ----
    f32x4 st[2][4];
#pragma unroll
    for (int ni = 0; ni < 4; ++ni) {
      const unsigned short* kp = Kh + (size_t)(kv0 + ni * 16 + c) * 64 + g * 8;
      s16x8 ka0 = *(const s16x8*)kp;
      s16x8 ka1 = *(const s16x8*)(kp + 32);
      f32x4 mv = *(const f32x4*)(mrow + kv0 + ni * 16 + g * 4);
#pragma unroll
      for (int mi = 0; mi < 2; ++mi) {
        f32x4 t = __builtin_amdgcn_mfma_f32_16x16x32_bf16(ka0, qb[mi][0], fz, 0, 0, 0);
        t = __builtin_amdgcn_mfma_f32_16x16x32_bf16(ka1, qb[mi][1], t, 0, 0, 0);
        st[mi][ni] = t + mv;
      }
    }

    // ---- online softmax, zero DS ops ----
    float al[2];
#pragma unroll
    for (int mi = 0; mi < 2; ++mi) {
      f32x4 t4 = vmax4(vmax4(st[mi][0], st[mi][1]), vmax4(st[mi][2], st[mi][3]));
      float tm = fmaxf(fmaxf(t4[0], t4[1]), fmaxf(t4[2], t4[3]));
      tm = redmax64(tm);
      float mn = fmaxf(mrun[mi], tm);
      al[mi] = __expf(mrun[mi] - mn);
      mrun[mi] = mn;
      f32x4 s4 = {0.f, 0.f, 0.f, 0.f};
#pragma unroll
      for (int ni = 0; ni < 4; ++ni)
#pragma unroll
        for (int r = 0; r < 4; ++r) {
          float p = __expf(st[mi][ni][r] - mn);
          st[mi][ni][r] = p;
          s4[r] += p;
        }
      float rs = (s4[0] + s4[1]) + (s4[2] + s4[3]);
      rs = redsum64(rs);
      lrun[mi] = lrun[mi] * al[mi] + rs;
    }
#pragma unroll
    for (int mi = 0; mi < 2; ++mi)
#pragma unroll
      for (int di = 0; di < 4; ++di) OT[mi][di] *= al[mi];

    // ---- build P^T fragments: cvt_pk + permlane32/16 swaps ----
    // dest dword m (elements k=8g+2m,+1) comes from source group ((8g+2m)&15)>>2.
    s16x8 pb[2][2];
#pragma unroll
    for (int mi = 0; mi < 2; ++mi)
#pragma unroll
      for (int ks = 0; ks < 2; ++ks) {
        uint32_t x  = pk_bf16(st[mi][2 * ks][0],     st[mi][2 * ks][1]);
        uint32_t y  = pk_bf16(st[mi][2 * ks + 1][0], st[mi][2 * ks + 1][1]);
        uint32_t x2 = pk_bf16(st[mi][2 * ks][2],     st[mi][2 * ks][3]);
        uint32_t y2 = pk_bf16(st[mi][2 * ks + 1][2], st[mi][2 * ks + 1][3]);
        asm("v_permlane32_swap_b32 %0, %1" : "+v"(x), "+v"(y));
        asm("v_permlane16_swap_b32 %0, %1" : "+v"(x), "+v"(y));   // x=dw0 y=dw2
        asm("v_permlane32_swap_b32 %0, %1" : "+v"(x2), "+v"(y2));
        asm("v_permlane16_swap_b32 %0, %1" : "+v"(x2), "+v"(y2)); // x2=dw1 y2=dw3
        u32x4 dw = {x, x2, y, y2};
        pb[mi][ks] = __builtin_bit_cast(s16x8, dw);
      }

    // ---- O^T += V^T P^T ----
#pragma unroll
    for (int di = 0; di < 4; ++di) {
      const unsigned short* vp = Vh + (size_t)(di * 16 + c) * 1152 + kv0;
      s16x8 va0 = *(const s16x8*)(vp + g * 8);
      s16x8 va1 = *(const s16x8*)(vp + 32 + g * 8);
#pragma unroll
      for (int mi = 0; mi < 2; ++mi) {
        OT[mi][di] =
            __builtin_amdgcn_mfma_f32_16x16x32_bf16(va0, pb[mi][0], OT[mi][di], 0, 0, 0);
        OT[mi][di] =
            __builtin_amdgcn_mfma_f32_16x16x32_bf16(va1, pb[mi][1], OT[mi][di], 0, 0, 0);
      }
    }
  }

  // ---- normalize + transpose via per-wave LDS + coalesced store ----
  float* Tw = &Tr[w][0][0];
  float inv[2] = {1.0f / lrun[0], 1.0f / lrun[1]};
#pragma unroll
  for (int mi = 0; mi < 2; ++mi)
#pragma unroll
    for (int di = 0; di < 4; ++di)
#pragma unroll
      for (int r = 0; r < 4; ++r)
        Tw[(di * 16 + g * 4 + r) * 33 + mi * 16 + c] = OT[mi][di][r] * inv[mi];

#pragma unroll
  for (int t = 0; t < 8; ++t) {
    const int qq = t * 4 + g;          // 0..31
    const int s = q0 + qq;
    const int dcol = c * 4;
    f32x4 v;
#pragma unroll
    for (int i = 0; i < 4; ++i) v[i] = Tw[(dcol + i) * 33 + qq];
    const size_t base =
        (s < 1024) ? ((size_t)(b * 1024 + s) * 1024 + h * 64)
                   : (8388608u + (size_t)(b * 128 + (s - 1024)) * 1024 + h * 64);
    *(f32x4*)(out + base + dcol) = v;
  }
}

// ---------------- launch ----------------
extern "C" void kernel_launch(void* const* d_in, const int* in_sizes, int n_in,
                              void* d_out, int out_size, void* d_ws, size_t ws_size,
                              hipStream_t stream) {
  const float* tok  = (const float*)d_in[0];
  const float* ent  = (const float*)d_in[1];
  const float* mask = (const float*)d_in[2];
  const float* qpos = (const float*)d_in[3];
  const float* Wq  = (const float*)d_in[4];  const float* bq  = (const float*)d_in[5];
  const float* Wk  = (const float*)d_in[6];  const float* bk  = (const float*)d_in[7];
  const float* Wv  = (const float*)d_in[8];  const float* bv  = (const float*)d_in[9];
  const float* Weq = (const float*)d_in[10]; const float* beq = (const float*)d_in[11];
  const float* Wek = (const float*)d_in[12]; const float* bek = (const float*)d_in[13];
  const float* Wev = (const float*)d_in[14]; const float* bev = (const float*)d_in[15];
  float* out = (float*)d_out;

  unsigned short* ws = (unsigned short*)d_ws;
  unsigned short* tokBF = ws;
  unsigned short* peBF  = ws + 8388608;
  unsigned short* entBF = ws + 9437184;
  unsigned short* WBF   = ws + 10485760;
  unsigned short* Qb    = ws + 16777216;
  unsigned short* Kb    = ws + 26214400;
  unsigned short* Vtb   = ws + 35651584;

  prep_kernel<<<2048, 256, 0, stream>>>(tok, ent, qpos, Wq, Wk, Wv, Weq, Wek, Wev, ws);
  proj_gemm<<<dim3(24, 72), 256, 0, stream>>>(tokBF, peBF, entBF, WBF,
                                              bq, bk, bv, beq, bek, bev,
                                              Qb, Kb, Vtb);
  attn_kernel<<<dim3(9, 128), 256, 0, stream>>>(Qb, Kb, Vtb, mask, out);
}

// Round 6
// 285.018 us; speedup vs baseline: 1.0930x; 1.0030x over previous
//
#include <hip/hip_runtime.h>
#include <cstdint>

// ---- problem constants ----
// B=8, T=1024, E=128, H=1024, NH=16, HD=64, S=T+E=1152
// inputs fp32; compute in bf16 MFMA with fp32 accum.

typedef __attribute__((ext_vector_type(8))) short s16x8;   // 8 bf16 (4 VGPR) MFMA operand
typedef __attribute__((ext_vector_type(4))) float f32x4;   // MFMA accumulator
typedef __attribute__((ext_vector_type(4))) unsigned short u16x4;
typedef __attribute__((ext_vector_type(4))) unsigned int u32x4;

#define DEVFN static __device__ __forceinline__

DEVFN unsigned short f2bf(float f) {  // RNE float->bf16
  uint32_t u = __builtin_bit_cast(uint32_t, f);
  u += 0x7fffu + ((u >> 16) & 1u);
  return (unsigned short)(u >> 16);
}

DEVFN void gload16(const void* g, void* lds) {  // async global->LDS, 16B/lane
  using GP = const __attribute__((address_space(1))) uint32_t*;
  using LP = __attribute__((address_space(3))) uint32_t*;
  __builtin_amdgcn_global_load_lds(
      reinterpret_cast<GP>(reinterpret_cast<uintptr_t>(g)),
      reinterpret_cast<LP>((uint32_t)reinterpret_cast<uintptr_t>(lds)),
      16, 0, 0);
}

// cross-lane pair values via permlane swaps (VALU-only, no DS latency).
// NOTE: byte-identical to the round-2 formulation that PASSED on HW.
DEVFN void sw16f(float v, float& x, float& y) {
  uint32_t a = __builtin_bit_cast(uint32_t, v), b = a;
  asm("v_permlane16_swap_b32 %0, %1" : "+v"(a), "+v"(b));
  x = __builtin_bit_cast(float, a);
  y = __builtin_bit_cast(float, b);
}
DEVFN void sw32f(float v, float& x, float& y) {
  uint32_t a = __builtin_bit_cast(uint32_t, v), b = a;
  asm("v_permlane32_swap_b32 %0, %1" : "+v"(a), "+v"(b));
  x = __builtin_bit_cast(float, a);
  y = __builtin_bit_cast(float, b);
}
DEVFN float redmax64(float v) {  // reduce-max across the 4 lane-groups
  float a, b;
  sw16f(v, a, b); v = fmaxf(a, b);
  sw32f(v, a, b); return fmaxf(a, b);
}
DEVFN float redsum64(float v) {
  float a, b;
  sw16f(v, a, b); v = a + b;
  sw32f(v, a, b); return a + b;
}
DEVFN uint32_t pk_bf16(float lo, float hi) {
  uint32_t r;
  asm("v_cvt_pk_bf16_f32 %0, %1, %2" : "=v"(r) : "v"(lo), "v"(hi));
  return r;
}
DEVFN f32x4 vmax4(f32x4 a, f32x4 b) {
  f32x4 r;
#pragma unroll
  for (int i = 0; i < 4; ++i) r[i] = fmaxf(a[i], b[i]);
  return r;
}

// ---------------- prep: fp32 -> bf16 casts (+ pos_ent fuse) ----------------
// ws bf16 layout (elements):
//   tokBF  @ 0        : 8388608   (tok [8192][1024])
//   peBF   @ 8388608  : 1048576   ((ent+qpos)*0.5 [1024][1024])
//   entBF  @ 9437184  : 1048576
//   WBF    @ 10485760 : 6*1048576 (row-major [n][k] = B^T layout)
//   Qb     @ 16777216 : 9437184   ([bh][s][64], pre-scaled by 0.125)
//   Kb     @ 26214400 : 9437184   ([bh][s][64])
//   Vtb    @ 35651584 : 9437184   ([bh][64][s] transposed for PV)
__global__ __launch_bounds__(256) void prep_kernel(
    const float* __restrict__ tok, const float* __restrict__ ent,
    const float* __restrict__ qpos,
    const float* __restrict__ W0, const float* __restrict__ W1,
    const float* __restrict__ W2, const float* __restrict__ W3,
    const float* __restrict__ W4, const float* __restrict__ W5,
    unsigned short* __restrict__ dst)
{
  const int NG = 4194304;
  for (int g = blockIdx.x * blockDim.x + threadIdx.x; g < NG;
       g += gridDim.x * blockDim.x) {
    int e = g << 2;
    f32x4 v;
    if (e < 8388608) {
      v = *(const f32x4*)(tok + e);
    } else if (e < 9437184) {
      int i = e - 8388608;
      f32x4 a = *(const f32x4*)(ent + i);
      f32x4 p = *(const f32x4*)(qpos + i);
      v = (a + p) * 0.5f;
    } else if (e < 10485760) {
      v = *(const f32x4*)(ent + (e - 9437184));
    } else {
      int i = e - 10485760;
      int wsel = i >> 20;
      const float* W = wsel == 0 ? W0 : wsel == 1 ? W1 : wsel == 2 ? W2
                     : wsel == 3 ? W3 : wsel == 4 ? W4 : W5;
      v = *(const f32x4*)(W + (i & 1048575));
    }
    u16x4 o;
#pragma unroll
    for (int j = 0; j < 4; ++j) o[j] = f2bf(v[j]);
    *(u16x4*)(dst + e) = o;
  }
}

// ---------------- projection GEMM (m97 structure) ----------------
__global__ __launch_bounds__(256) void proj_gemm(
    const unsigned short* __restrict__ Atok, const unsigned short* __restrict__ Ape,
    const unsigned short* __restrict__ Aent, const unsigned short* __restrict__ Wb6,
    const float* __restrict__ b0, const float* __restrict__ b1,
    const float* __restrict__ b2, const float* __restrict__ b3,
    const float* __restrict__ b4, const float* __restrict__ b5,
    unsigned short* __restrict__ Qo, unsigned short* __restrict__ Ko,
    unsigned short* __restrict__ Vt)
{
  __shared__ __align__(16) unsigned short As[128 * 32];
  __shared__ __align__(16) unsigned short Bs[128 * 32];

  const int tid = threadIdx.x;
  const int l = tid & 63, w = tid >> 6;
  const int lr = l & 15, lg = l >> 4;
  const int bx = blockIdx.x, by = blockIdx.y;
  const int which = bx >> 3;            // 0=Q 1=K 2=V
  const int n0l = (bx & 7) << 7;
  const bool entm = by >= 64;
  const int byl = entm ? by - 64 : by;
  const int wsel = which + (entm ? 3 : 0);
  const unsigned short* A = entm ? (which == 2 ? Aent : Ape) : Atok;
  const unsigned short* Wp = Wb6 + (size_t)wsel * 1048576;
  const float* bias = entm ? (which == 0 ? b3 : which == 1 ? b4 : b5)
                           : (which == 0 ? b0 : which == 1 ? b1 : b2);
  const int bShift = entm ? 7 : 10;
  const int sBase = entm ? 1024 : 0;
  const float qscale = (which == 0) ? 0.125f : 1.0f;

  const int c0 = w * 2, c1 = w * 2 + 1;
  const int sr0 = c0 * 16 + (l >> 2), sr1 = c1 * 16 + (l >> 2);
  const int sc0 = ((l & 3) * 8) ^ (((sr0 >> 1) & 3) << 3);
  const int sc1 = ((l & 3) * 8) ^ (((sr1 >> 1) & 3) << 3);
  const unsigned short* gA0 = A + (size_t)(byl * 128 + sr0) * 1024 + sc0;
  const unsigned short* gA1 = A + (size_t)(byl * 128 + sr1) * 1024 + sc1;
  const unsigned short* gB0 = Wp + (size_t)(n0l + sr0) * 1024 + sc0;
  const unsigned short* gB1 = Wp + (size_t)(n0l + sr1) * 1024 + sc1;
  unsigned short* lA0 = As + c0 * 512; unsigned short* lA1 = As + c1 * 512;
  unsigned short* lB0 = Bs + c0 * 512; unsigned short* lB1 = Bs + c1 * 512;

  const int wr = w >> 1, wc = w & 1;
  int offA[4], offB[4];
#pragma unroll
  for (int mi = 0; mi < 4; ++mi) {
    int row = wr * 64 + mi * 16 + lr;
    offA[mi] = row * 32 + ((lg * 8) ^ (((row >> 1) & 3) << 3));
  }
#pragma unroll
  for (int ni = 0; ni < 4; ++ni) {
    int row = wc * 64 + ni * 16 + lr;
    offB[ni] = row * 32 + ((lg * 8) ^ (((row >> 1) & 3) << 3));
  }

  f32x4 acc[4][4] = {};
  for (int kt = 0; kt < 32; ++kt) {
    const int ko = kt * 32;
    gload16(gA0 + ko, lA0);
    gload16(gA1 + ko, lA1);
    gload16(gB0 + ko, lB0);
    gload16(gB1 + ko, lB1);
    __syncthreads();
    s16x8 a[4], b[4];
#pragma unroll
    for (int mi = 0; mi < 4; ++mi) a[mi] = *(const s16x8*)(As + offA[mi]);
#pragma unroll
    for (int ni = 0; ni < 4; ++ni) b[ni] = *(const s16x8*)(Bs + offB[ni]);
#pragma unroll
    for (int mi = 0; mi < 4; ++mi)
#pragma unroll
      for (int ni = 0; ni < 4; ++ni)
        acc[mi][ni] = __builtin_amdgcn_mfma_f32_16x16x32_bf16(
            a[mi], b[ni], acc[mi][ni], 0, 0, 0);
    __syncthreads();
  }

  const int bMask = (1 << bShift) - 1;
#pragma unroll
  for (int mi = 0; mi < 4; ++mi) {
    const int i0 = byl * 128 + wr * 64 + mi * 16 + lg * 4;
#pragma unroll
    for (int ni = 0; ni < 4; ++ni) {
      const int j = n0l + wc * 64 + ni * 16 + lr;
      const float bv = bias[j];
      const int h = j >> 6, d = j & 63;
      if (which < 2) {
        unsigned short* dst = (which == 0) ? Qo : Ko;
#pragma unroll
        for (int r = 0; r < 4; ++r) {
          const int i = i0 + r;
          const int bidx = i >> bShift;
          const int s = sBase + (i & bMask);
          dst[((size_t)(bidx * 16 + h) * 1152 + s) * 64 + d] =
              f2bf((acc[mi][ni][r] + bv) * qscale);
        }
      } else {
        const int bidx = i0 >> bShift;
        const int s0 = sBase + (i0 & bMask);
        u16x4 pk;
#pragma unroll
        for (int r = 0; r < 4; ++r) pk[r] = f2bf(acc[mi][ni][r] + bv);
        *(u16x4*)(Vt + ((size_t)(bidx * 16 + h) * 64 + d) * 1152 + s0) = pk;
      }
    }
  }
}

// ---------------- flash attention (round-2 structure, XCD-remapped grid) ---
// ONLY change vs the round-2 PASSING kernel: 1D grid 1152 = 8 XCD groups x
// (9 q-tiles fastest, 16 bh-groups) so the 9 blocks sharing one bh's K/V are
// dispatch-adjacent on one XCD (L2 reuse). Mapping is bijective; per-block
// computation is identical to round 2.
__global__ __launch_bounds__(256) void attn_kernel(
    const unsigned short* __restrict__ Q, const unsigned short* __restrict__ K,
    const unsigned short* __restrict__ Vt, const float* __restrict__ mask,
    float* __restrict__ out)
{
  __shared__ float Tr[4][64][33];  // per-wave O^T -> O transpose buffer
  const int tid = threadIdx.x, l = tid & 63, w = tid >> 6;
  const int c = l & 15, g = l >> 4;
  const int nblk = blockIdx.x;
  const int xcd = nblk & 7, jj = nblk >> 3;   // jj 0..143
  const int qt = jj % 9;
  const int bh = (jj / 9) * 8 + xcd;
  const int b = bh >> 4, h = bh & 15;
  const unsigned short* Qh = Q + (size_t)bh * 73728;
  const unsigned short* Kh = K + (size_t)bh * 73728;
  const unsigned short* Vh = Vt + (size_t)bh * 73728;  // [64][1152]
  const float* mrow = mask + b * 1152;
  const int q0 = qt * 128 + w * 32;
  const f32x4 fz = {0.f, 0.f, 0.f, 0.f};

  // Q as B-operand: lane holds Q[q0+mi*16+c][ds*32 + g*8 + j]
  s16x8 qb[2][2];
#pragma unroll
  for (int mi = 0; mi < 2; ++mi)
#pragma unroll
    for (int ds = 0; ds < 2; ++ds)
      qb[mi][ds] =
          *(const s16x8*)(Qh + (size_t)(q0 + mi * 16 + c) * 64 + ds * 32 + g * 8);

  f32x4 OT[2][4] = {};              // O^T[d=di*16+g*4+r][q=mi*16+c]
  float mrun[2] = {-1e30f, -1e30f}, lrun[2] = {0.f, 0.f};

  for (int kv0 = 0; kv0 < 1152; kv0 += 64) {
    // ---- S^T = K Q^T (Q pre-scaled), + mask ----
    f32x4 st[2][4];
#pragma unroll
    for (int ni = 0; ni < 4; ++ni) {
      const unsigned short* kp = Kh + (size_t)(kv0 + ni * 16 + c) * 64 + g * 8;
      s16x8 ka0 = *(const s16x8*)kp;
      s16x8 ka1 = *(const s16x8*)(kp + 32);
      f32x4 mv = *(const f32x4*)(mrow + kv0 + ni * 16 + g * 4);
#pragma unroll
      for (int mi = 0; mi < 2; ++mi) {
        f32x4 t = __builtin_amdgcn_mfma_f32_16x16x32_bf16(ka0, qb[mi][0], fz, 0, 0, 0);
        t = __builtin_amdgcn_mfma_f32_16x16x32_bf16(ka1, qb[mi][1], t, 0, 0, 0);
        st[mi][ni] = t + mv;
      }
    }

    // ---- online softmax, zero DS ops ----
    float al[2];
#pragma unroll
    for (int mi = 0; mi < 2; ++mi) {
      f32x4 t4 = vmax4(vmax4(st[mi][0], st[mi][1]), vmax4(st[mi][2], st[mi][3]));
      float tm = fmaxf(fmaxf(t4[0], t4[1]), fmaxf(t4[2], t4[3]));
      tm = redmax64(tm);
      float mn = fmaxf(mrun[mi], tm);
      al[mi] = __expf(mrun[mi] - mn);
      mrun[mi] = mn;
      f32x4 s4 = {0.f, 0.f, 0.f, 0.f};
#pragma unroll
      for (int ni = 0; ni < 4; ++ni)
#pragma unroll
        for (int r = 0; r < 4; ++r) {
          float p = __expf(st[mi][ni][r] - mn);
          st[mi][ni][r] = p;
          s4[r] += p;
        }
      float rs = (s4[0] + s4[1]) + (s4[2] + s4[3]);
      rs = redsum64(rs);
      lrun[mi] = lrun[mi] * al[mi] + rs;
    }
#pragma unroll
    for (int mi = 0; mi < 2; ++mi)
#pragma unroll
      for (int di = 0; di < 4; ++di) OT[mi][di] *= al[mi];

    // ---- build P^T fragments: cvt_pk + permlane32/16 swaps ----
    s16x8 pb[2][2];
#pragma unroll
    for (int mi = 0; mi < 2; ++mi)
#pragma unroll
      for (int ks = 0; ks < 2; ++ks) {
        uint32_t x  = pk_bf16(st[mi][2 * ks][0],     st[mi][2 * ks][1]);
        uint32_t y  = pk_bf16(st[mi][2 * ks + 1][0], st[mi][2 * ks + 1][1]);
        uint32_t x2 = pk_bf16(st[mi][2 * ks][2],     st[mi][2 * ks][3]);
        uint32_t y2 = pk_bf16(st[mi][2 * ks + 1][2], st[mi][2 * ks + 1][3]);
        asm("v_permlane32_swap_b32 %0, %1" : "+v"(x), "+v"(y));
        asm("v_permlane16_swap_b32 %0, %1" : "+v"(x), "+v"(y));   // x=dw0 y=dw2
        asm("v_permlane32_swap_b32 %0, %1" : "+v"(x2), "+v"(y2));
        asm("v_permlane16_swap_b32 %0, %1" : "+v"(x2), "+v"(y2)); // x2=dw1 y2=dw3
        u32x4 dw = {x, x2, y, y2};
        pb[mi][ks] = __builtin_bit_cast(s16x8, dw);
      }

    // ---- O^T += V^T P^T ----
#pragma unroll
    for (int di = 0; di < 4; ++di) {
      const unsigned short* vp = Vh + (size_t)(di * 16 + c) * 1152 + kv0;
      s16x8 va0 = *(const s16x8*)(vp + g * 8);
      s16x8 va1 = *(const s16x8*)(vp + 32 + g * 8);
#pragma unroll
      for (int mi = 0; mi < 2; ++mi) {
        OT[mi][di] =
            __builtin_amdgcn_mfma_f32_16x16x32_bf16(va0, pb[mi][0], OT[mi][di], 0, 0, 0);
        OT[mi][di] =
            __builtin_amdgcn_mfma_f32_16x16x32_bf16(va1, pb[mi][1], OT[mi][di], 0, 0, 0);
      }
    }
  }

  // ---- normalize + transpose via per-wave LDS + coalesced store ----
  float* Tw = &Tr[w][0][0];
  float inv[2] = {1.0f / lrun[0], 1.0f / lrun[1]};
#pragma unroll
  for (int mi = 0; mi < 2; ++mi)
#pragma unroll
    for (int di = 0; di < 4; ++di)
#pragma unroll
      for (int r = 0; r < 4; ++r)
        Tw[(di * 16 + g * 4 + r) * 33 + mi * 16 + c] = OT[mi][di][r] * inv[mi];

#pragma unroll
  for (int t = 0; t < 8; ++t) {
    const int qq = t * 4 + g;          // 0..31
    const int s = q0 + qq;
    const int dcol = c * 4;
    f32x4 v;
#pragma unroll
    for (int i = 0; i < 4; ++i) v[i] = Tw[(dcol + i) * 33 + qq];
    const size_t base =
        (s < 1024) ? ((size_t)(b * 1024 + s) * 1024 + h * 64)
                   : (8388608u + (size_t)(b * 128 + (s - 1024)) * 1024 + h * 64);
    *(f32x4*)(out + base + dcol) = v;
  }
}

// ---------------- launch ----------------
extern "C" void kernel_launch(void* const* d_in, const int* in_sizes, int n_in,
                              void* d_out, int out_size, void* d_ws, size_t ws_size,
                              hipStream_t stream) {
  const float* tok  = (const float*)d_in[0];
  const float* ent  = (const float*)d_in[1];
  const float* mask = (const float*)d_in[2];
  const float* qpos = (const float*)d_in[3];
  const float* Wq  = (const float*)d_in[4];  const float* bq  = (const float*)d_in[5];
  const float* Wk  = (const float*)d_in[6];  const float* bk  = (const float*)d_in[7];
  const float* Wv  = (const float*)d_in[8];  const float* bv  = (const float*)d_in[9];
  const float* Weq = (const float*)d_in[10]; const float* beq = (const float*)d_in[11];
  const float* Wek = (const float*)d_in[12]; const float* bek = (const float*)d_in[13];
  const float* Wev = (const float*)d_in[14]; const float* bev = (const float*)d_in[15];
  float* out = (float*)d_out;

  unsigned short* ws = (unsigned short*)d_ws;
  unsigned short* tokBF = ws;
  unsigned short* peBF  = ws + 8388608;
  unsigned short* entBF = ws + 9437184;
  unsigned short* WBF   = ws + 10485760;
  unsigned short* Qb    = ws + 16777216;
  unsigned short* Kb    = ws + 26214400;
  unsigned short* Vtb   = ws + 35651584;

  prep_kernel<<<2048, 256, 0, stream>>>(tok, ent, qpos, Wq, Wk, Wv, Weq, Wek, Wev, ws);
  proj_gemm<<<dim3(24, 72), 256, 0, stream>>>(tokBF, peBF, entBF, WBF,
                                              bq, bk, bv, beq, bek, bev,
                                              Qb, Kb, Vtb);
  attn_kernel<<<1152, 256, 0, stream>>>(Qb, Kb, Vtb, mask, out);
}